// Round 1
// baseline (258.881 us; speedup 1.0000x reference)
//
#include <hip/hip_runtime.h>

#define S_LEN 2048
#define NHQ 8
#define NKV 2
#define HD 256

typedef __attribute__((ext_vector_type(8))) short bf16x8;
typedef __attribute__((ext_vector_type(4))) short bf16x4;
typedef __attribute__((ext_vector_type(4))) float f32x4;

__device__ __forceinline__ short f2bf(float f) {
    unsigned u = __builtin_bit_cast(unsigned, f);
    u += 0x7FFFu + ((u >> 16) & 1u);
    return (short)(u >> 16);
}
__device__ __forceinline__ float bf2f(short s) {
    unsigned u = ((unsigned)(unsigned short)s) << 16;
    return __builtin_bit_cast(float, u);
}

// ---------------- fp32 -> bf16 convert ----------------
__global__ __launch_bounds__(256) void cvt_kernel(const float* __restrict__ in,
                                                  short* __restrict__ out, int n) {
    int i = (blockIdx.x * 256 + threadIdx.x) * 4;
    if (i + 3 < n) {
        float4 f = *(const float4*)(in + i);
        bf16x4 o;
        o[0] = f2bf(f.x); o[1] = f2bf(f.y); o[2] = f2bf(f.z); o[3] = f2bf(f.w);
        *(bf16x4*)(out + i) = o;
    }
}

// ---------------- GEMM: C[MxN] = A[MxK](bf16) @ B[KxN](bf16) ----------------
// block 256 thr = 4 waves, each wave 32x32 of a 64x64 tile. BK=32.
template<int WRITE_BF16>
__global__ __launch_bounds__(256) void gemm_kernel(const short* __restrict__ A,
                                                   const short* __restrict__ B,
                                                   void* __restrict__ Cv,
                                                   int M, int N, int K) {
    __shared__ short As[64 * 32];
    __shared__ short Bs[64 * 32];   // transposed: Bs[n][k]
    const int t = threadIdx.x;
    const int lane = t & 63, wid = t >> 6;
    const int lr = lane & 15, lg = lane >> 4;
    const int m0 = blockIdx.y * 64, n0 = blockIdx.x * 64;
    const int wm = (wid >> 1) * 32, wn = (wid & 1) * 32;

    f32x4 acc[2][2];
    for (int i = 0; i < 2; i++) for (int j = 0; j < 2; j++)
        acc[i][j] = (f32x4){0.f, 0.f, 0.f, 0.f};

    const int ar = t >> 2, ac = (t & 3) * 8;   // A stage
    const int bn = t & 63, bk0 = (t >> 6) * 8; // B stage

    for (int k0 = 0; k0 < K; k0 += 32) {
        __syncthreads();
        *(bf16x8*)&As[ar * 32 + ac] = *(const bf16x8*)&A[(long)(m0 + ar) * K + k0 + ac];
        #pragma unroll
        for (int i = 0; i < 8; i++)
            Bs[bn * 32 + bk0 + i] = B[(long)(k0 + bk0 + i) * N + n0 + bn];
        __syncthreads();
        #pragma unroll
        for (int mi = 0; mi < 2; mi++) {
            bf16x8 af = *(const bf16x8*)&As[(wm + mi * 16 + lr) * 32 + lg * 8];
            #pragma unroll
            for (int ni = 0; ni < 2; ni++) {
                bf16x8 bfr = *(const bf16x8*)&Bs[(wn + ni * 16 + lr) * 32 + lg * 8];
                acc[mi][ni] = __builtin_amdgcn_mfma_f32_16x16x32_bf16(af, bfr, acc[mi][ni], 0, 0, 0);
            }
        }
    }
    #pragma unroll
    for (int mi = 0; mi < 2; mi++)
    #pragma unroll
    for (int ni = 0; ni < 2; ni++)
    #pragma unroll
    for (int r = 0; r < 4; r++) {
        long row = m0 + wm + mi * 16 + lg * 4 + r;
        long col = n0 + wn + ni * 16 + lr;
        float v = acc[mi][ni][r];
        if (WRITE_BF16) ((short*)Cv)[row * N + col] = f2bf(v);
        else            ((float*)Cv)[row * N + col] = v;
    }
}

// ---------------- RMSNorm + partial RoPE ----------------
// one wave per (token, head) vector of 256; lane owns dims [4*lane, 4*lane+4)
__global__ __launch_bounds__(256) void norm_rope_kernel(
    const short* __restrict__ in, short* __restrict__ out,
    const float* __restrict__ w, const float* __restrict__ cosb,
    const float* __restrict__ sinb, int H, long ob, long oh, long os) {
    int vec = blockIdx.x * 4 + (threadIdx.x >> 6);
    int lane = threadIdx.x & 63;
    int token = vec / H, head = vec % H;
    int b = token / S_LEN, s = token % S_LEN;

    bf16x4 xv = *(const bf16x4*)(in + (long)vec * 256 + lane * 4);
    float x0 = bf2f(xv[0]), x1 = bf2f(xv[1]), x2 = bf2f(xv[2]), x3 = bf2f(xv[3]);
    float ss = x0 * x0 + x1 * x1 + x2 * x2 + x3 * x3;
    #pragma unroll
    for (int m = 1; m < 64; m <<= 1) ss += __shfl_xor(ss, m);
    float inv = rsqrtf(ss * (1.f / 256.f) + 1e-6f);

    float4 wv = *(const float4*)(w + lane * 4);
    float y0 = x0 * inv * (1.f + wv.x);
    float y1 = x1 * inv * (1.f + wv.y);
    float y2 = x2 * inv * (1.f + wv.z);
    float y3 = x3 * inv * (1.f + wv.w);

    if (lane < 16) {  // dims < 64: rope pairs (4l,4l+1),(4l+2,4l+3) using idx 2l,2l+1
        float2 c = *(const float2*)&cosb[s * 32 + lane * 2];
        float2 sn = *(const float2*)&sinb[s * 32 + lane * 2];
        float a0 = y0 * c.x - y1 * sn.x, b0 = y0 * sn.x + y1 * c.x;
        float a1 = y2 * c.y - y3 * sn.y, b1 = y2 * sn.y + y3 * c.y;
        y0 = a0; y1 = b0; y2 = a1; y3 = b1;
    }
    long oidx = (long)b * ob + (long)head * oh + (long)s * os + lane * 4;
    bf16x4 o; o[0] = f2bf(y0); o[1] = f2bf(y1); o[2] = f2bf(y2); o[3] = f2bf(y3);
    *(bf16x4*)(out + oidx) = o;
}

// ---------------- V transpose: vf[b][s][kv][d] -> vr[b][kv][d][s] ----------------
__global__ __launch_bounds__(256) void transpose_v_kernel(const short* __restrict__ vf,
                                                          short* __restrict__ vr) {
    __shared__ short tile[64][65];
    int s0 = blockIdx.x * 64, d0 = blockIdx.y * 64;
    int bkv = blockIdx.z; int b = bkv >> 1, kv = bkv & 1;
    int t = threadIdx.x;
    #pragma unroll
    for (int i = 0; i < 16; i++) {
        int flat = i * 256 + t; int si = flat >> 6, di = flat & 63;
        tile[si][di] = vf[(long)(b * S_LEN + s0 + si) * 512 + kv * 256 + d0 + di];
    }
    __syncthreads();
    #pragma unroll
    for (int i = 0; i < 16; i++) {
        int flat = i * 256 + t; int di = flat >> 6, si = flat & 63;
        vr[(long)(bkv * 256 + d0 + di) * S_LEN + s0 + si] = tile[si][di];
    }
}

// ---------------- flash attention ----------------
// block: 256 thr = 4 waves, 64 q-rows (16/wave), key tiles of 64 staged in LDS.
__global__ __launch_bounds__(256) void flash_kernel(const short* __restrict__ Q,
                                                    const short* __restrict__ Kt,
                                                    const short* __restrict__ Vt,
                                                    short* __restrict__ O) {
    __shared__ short Ks[64 * 264];   // [key][d], pitch 264 (pad 16B -> 2-way banks)
    __shared__ short Vs[256 * 72];   // [d][key], pitch 72
    __shared__ short Ps[4 * 16 * 32];

    int idx = blockIdx.x;
    int half = idx >> 8, rem = idx & 255;
    int qtr = rem >> 4;
    int qt = half ? (31 - qtr) : qtr;       // balance causal work across CUs
    int hb = rem & 15, h = hb & 7, b = hb >> 3;
    int kv = h >> 2;
    int t = threadIdx.x, lane = t & 63, wid = t >> 6;
    int lr = lane & 15, lg = lane >> 4;
    int qb = qt * 64, q0 = qb + wid * 16;

    bf16x8 qf[8];
    {
        long base = ((long)(b * S_LEN + q0 + lr) * NHQ + h) * HD + lg * 8;
        #pragma unroll
        for (int kd = 0; kd < 8; kd++) qf[kd] = *(const bf16x8*)&Q[base + kd * 32];
    }
    f32x4 acc[16];
    #pragma unroll
    for (int i = 0; i < 16; i++) acc[i] = (f32x4){0.f, 0.f, 0.f, 0.f};
    float m[4], l[4];
    #pragma unroll
    for (int r = 0; r < 4; r++) { m[r] = -1e30f; l[r] = 0.f; }

    const short* Kbase = Kt + (long)(b * NKV + kv) * S_LEN * HD;
    const short* Vbase = Vt + (long)(b * NKV + kv) * HD * S_LEN;

    int ntiles = qt + 1;
    for (int tt = 0; tt < ntiles; tt++) {
        int k0 = tt * 64;
        __syncthreads();
        #pragma unroll
        for (int i = 0; i < 8; i++) {     // K: 64 x 256
            int c = i * 256 + t;
            int row = c >> 5, col = (c & 31) * 8;
            *(bf16x8*)&Ks[row * 264 + col] = *(const bf16x8*)&Kbase[(long)(k0 + row) * HD + col];
        }
        #pragma unroll
        for (int i = 0; i < 8; i++) {     // V^T: 256 x 64
            int c = i * 256 + t;
            int row = c >> 3, col = (c & 7) * 8;
            *(bf16x8*)&Vs[row * 72 + col] = *(const bf16x8*)&Vbase[(long)row * S_LEN + k0 + col];
        }
        __syncthreads();

        #pragma unroll
        for (int kt2 = 0; kt2 < 2; kt2++) {
            f32x4 sc[2];
            sc[0] = (f32x4){0.f, 0.f, 0.f, 0.f}; sc[1] = sc[0];
            #pragma unroll
            for (int kd = 0; kd < 8; kd++) {
                bf16x8 kf0 = *(const bf16x8*)&Ks[(kt2 * 32 + lr) * 264 + kd * 32 + lg * 8];
                bf16x8 kf1 = *(const bf16x8*)&Ks[(kt2 * 32 + 16 + lr) * 264 + kd * 32 + lg * 8];
                sc[0] = __builtin_amdgcn_mfma_f32_16x16x32_bf16(qf[kd], kf0, sc[0], 0, 0, 0);
                sc[1] = __builtin_amdgcn_mfma_f32_16x16x32_bf16(qf[kd], kf1, sc[1], 0, 0, 0);
            }
            int kc0 = k0 + kt2 * 32 + lr, kc1 = kc0 + 16;
            float f[4], p0[4], p1[4];
            #pragma unroll
            for (int r = 0; r < 4; r++) {
                int qrow = q0 + lg * 4 + r;
                float s0 = sc[0][r] * 0.0625f;
                float s1 = sc[1][r] * 0.0625f;
                if (kc0 > qrow) s0 = -1e30f;
                if (kc1 > qrow) s1 = -1e30f;
                float rm = fmaxf(s0, s1);
                rm = fmaxf(rm, __shfl_xor(rm, 1));
                rm = fmaxf(rm, __shfl_xor(rm, 2));
                rm = fmaxf(rm, __shfl_xor(rm, 4));
                rm = fmaxf(rm, __shfl_xor(rm, 8));
                float mn = fmaxf(m[r], rm);
                f[r] = __expf(m[r] - mn);
                m[r] = mn;
                p0[r] = __expf(s0 - mn);
                p1[r] = __expf(s1 - mn);
                float sum = p0[r] + p1[r];
                sum += __shfl_xor(sum, 1);
                sum += __shfl_xor(sum, 2);
                sum += __shfl_xor(sum, 4);
                sum += __shfl_xor(sum, 8);
                l[r] = l[r] * f[r] + sum;
            }
            #pragma unroll
            for (int i = 0; i < 16; i++)
                #pragma unroll
                for (int r = 0; r < 4; r++) acc[i][r] *= f[r];

            short* Pw = &Ps[wid * 512];
            #pragma unroll
            for (int r = 0; r < 4; r++) {
                Pw[(lg * 4 + r) * 32 + lr]      = f2bf(p0[r]);
                Pw[(lg * 4 + r) * 32 + 16 + lr] = f2bf(p1[r]);
            }
            __syncthreads();   // make P visible for cross-lane fragment read
            bf16x8 pf = *(const bf16x8*)&Pw[lr * 32 + lg * 8];
            #pragma unroll
            for (int cf = 0; cf < 16; cf++) {
                bf16x8 vfr = *(const bf16x8*)&Vs[(cf * 16 + lr) * 72 + kt2 * 32 + lg * 8];
                acc[cf] = __builtin_amdgcn_mfma_f32_16x16x32_bf16(pf, vfr, acc[cf], 0, 0, 0);
            }
            __syncthreads();   // protect Ps before next kt2 overwrite
        }
    }
    #pragma unroll
    for (int cf = 0; cf < 16; cf++)
    #pragma unroll
    for (int r = 0; r < 4; r++) {
        int qrow = q0 + lg * 4 + r;
        O[((long)(b * S_LEN + qrow) * NHQ + h) * HD + cf * 16 + lr] = f2bf(acc[cf][r] / l[r]);
    }
}

extern "C" void kernel_launch(void* const* d_in, const int* in_sizes, int n_in,
                              void* d_out, int out_size, void* d_ws, size_t ws_size,
                              hipStream_t stream) {
    const float* x    = (const float*)d_in[0];
    const float* cosb = (const float*)d_in[1];
    const float* sinb = (const float*)d_in[2];
    // d_in[3] = mask: equivalent to causal; computed analytically in-kernel
    const float* wq   = (const float*)d_in[4];
    const float* wk   = (const float*)d_in[5];
    const float* wv   = (const float*)d_in[6];
    const float* wo   = (const float*)d_in[7];
    const float* qnw  = (const float*)d_in[8];
    const float* knw  = (const float*)d_in[9];
    float* out = (float*)d_out;

    char* ws = (char*)d_ws;
    short* xb  = (short*)(ws + 0);          // 4096x512   bf16
    short* wqb = (short*)(ws + 4194304);    // 512x2048
    short* wkb = (short*)(ws + 6291456);    // 512x512
    short* wvb = (short*)(ws + 6815744);    // 512x512
    short* wob = (short*)(ws + 7340032);    // 2048x512
    short* qf  = (short*)(ws + 9437184);    // 4096x2048 (q raw -> roped in place)
    short* kf  = (short*)(ws + 26214400);   // 4096x512
    short* vf  = (short*)(ws + 30408704);   // 4096x512
    short* kr  = (short*)(ws + 34603008);   // [b][kv][s][d]
    short* vr  = (short*)(ws + 38797312);   // [b][kv][d][s]
    short* ao  = (short*)(ws + 42991616);   // 4096x2048

    cvt_kernel<<<2048, 256, 0, stream>>>(x,  xb,  2097152);
    cvt_kernel<<<1024, 256, 0, stream>>>(wq, wqb, 1048576);
    cvt_kernel<<<256,  256, 0, stream>>>(wk, wkb, 262144);
    cvt_kernel<<<256,  256, 0, stream>>>(wv, wvb, 262144);
    cvt_kernel<<<1024, 256, 0, stream>>>(wo, wob, 1048576);

    gemm_kernel<1><<<dim3(32, 64), 256, 0, stream>>>(xb, wqb, qf, 4096, 2048, 512);
    gemm_kernel<1><<<dim3(8, 64),  256, 0, stream>>>(xb, wkb, kf, 4096, 512, 512);
    gemm_kernel<1><<<dim3(8, 64),  256, 0, stream>>>(xb, wvb, vf, 4096, 512, 512);

    norm_rope_kernel<<<8192, 256, 0, stream>>>(qf, qf, qnw, cosb, sinb, 8,
                                               4194304L, 256L, 2048L);
    norm_rope_kernel<<<2048, 256, 0, stream>>>(kf, kr, knw, cosb, sinb, 2,
                                               1048576L, 524288L, 256L);
    transpose_v_kernel<<<dim3(32, 4, 4), 256, 0, stream>>>(vf, vr);

    flash_kernel<<<512, 256, 0, stream>>>(qf, kr, vr, ao);

    gemm_kernel<0><<<dim3(8, 64), 256, 0, stream>>>(ao, wob, out, 4096, 512, 2048);
}